// Round 17
// baseline (221.396 us; speedup 1.0000x reference)
//
#include <hip/hip_runtime.h>
#include <stdint.h>

// VectorQuantizer (eval fwd): inputs [64,64,32,32] f32 NCHW, embedding [1024,64] f32.
// Outputs concatenated: quantized [64,64,32,32] f32, loss scalar, perplexity scalar.
//
// Round-17: r14 inner loop (proven: VGPR 56, absmax 0.0) at 8 waves/SIMD.
//  r13-r16 synthesis: VALU busy-time is invariant ~71us (pk_fma issues at
//  ~4cyc/wave = scalar FLOP rate; 157TF spec IS the scalar rate). Wall =
//  71us / utilization. r14 = 58% util at 4 waves/SIMD (grid-capped 2 blk/CU).
//  This round: k-split across block pairs (block: 128 rows x 512 codes,
//  8 waves x 64 codes) -> grid 1024 = 4 blk/CU = 8 waves/SIMD.
//  LDS trimmed to 39936B (<40KB for 4 blk/CU): XSTR 66 (2-way bank alias =
//  free, m136), merge arrays f32+u16. Epilogue = separate r6-proven kernel
//  merging the 2 per-row partials (k-ranges ascending -> first-occurrence
//  argmin preserved) + gather/STE/loss/counts.
// dist = ||e||^2 - 2 x.e, identical op order to r13/r14/r16 (absmax 0.0).

#define K_CODES 1024
#define DIM 64
#define HW 1024          // 32*32
#define N_ROWS 65536
#define OUT_ELEMS 4194304
#define XSTR 66          // x row stride in dwords (2-way bank alias: free)
#define RPB 128          // rows per block

// ws layout (float indices)
#define WS_E2   0        // 1024 f32: ||e_k||^2
#define WS_CNT  1024     // 1024 u32: counts
#define WS_LOSS 2048     // 1 f32
#define WS_PD   4096     // 2*N f32 partial dists, then 2*N i32 partial ks
#define WS_PK   (4096 + 2 * N_ROWS)
#define WS_NEED_BYTES ((size_t)(WS_PK + 2 * N_ROWS) * 4)

__global__ void vq_init(const float* __restrict__ emb, float* __restrict__ ws) {
    const int k = blockIdx.x * blockDim.x + threadIdx.x;  // 1024 threads total
    if (k < K_CODES) {
        const float4* e4 = reinterpret_cast<const float4*>(emb + k * DIM);
        float s = 0.f;
#pragma unroll
        for (int i = 0; i < DIM / 4; ++i) {
            float4 v = e4[i];
            s += v.x * v.x + v.y * v.y + v.z * v.z + v.w * v.w;
        }
        ws[WS_E2 + k] = s;
        reinterpret_cast<unsigned int*>(ws)[WS_CNT + k] = 0u;
    }
    if (blockIdx.x == 0 && threadIdx.x == 0) ws[WS_LOSS] = 0.f;
}

// ---- argmin: block (rg, kh): rows [rg*128, +128), codes [kh*512, +512) ----
__global__ __launch_bounds__(512, 2) void vq_argmin(
    const float* __restrict__ in, const float* __restrict__ emb,
    float* __restrict__ ws)
{
    __shared__ __align__(16) float xs[RPB * XSTR];   // 33792 B
    __shared__ float          bwd[8][RPB];           // 4096 B
    __shared__ unsigned short bwk[8][RPB];           // 2048 B  -> total 39936 B

    const int t = threadIdx.x;
    const int w = t >> 6;        // wave id 0..7
    const int l = t & 63;
    const int w_u = __builtin_amdgcn_readfirstlane(w);   // SGPR wave id

    const int blk = blockIdx.x;
    const int rg = blk >> 1, kh = blk & 1;
    const int row0 = rg * RPB;
    const int b = row0 >> 10, hw0 = row0 & 1023;   // 128 | 1024 -> one b per block
    const float* xin = in + b * (DIM * HW) + hw0;

    // ---- stage x tile: thread (w,l): rows l, l+64, channels [8w, 8w+8) ----
#pragma unroll
    for (int rr = 0; rr < 2; ++rr) {
        const int r = rr * 64 + l;
#pragma unroll
        for (int cc = 0; cc < 8; ++cc) {
            const int c = w * 8 + cc;
            xs[r * XSTR + c] = xin[c * HW + r];   // lanes l consecutive -> coalesced
        }
    }
    __syncthreads();

    // ---- argmin over this wave's 64 codes for both rows (k0 wave-uniform) ----
    const float* e2 = ws + WS_E2;
    const float* x0 = xs + l * XSTR;
    const float* x1 = xs + (l + 64) * XSTR;
    float best0 = 3.4e38f, best1 = 3.4e38f;
    int   bk0 = 0, bk1 = 0;
    const int k0 = kh * 512 + w_u * 64;

    for (int kg = 0; kg < 64; kg += 8) {
        float2 acc0[8], acc1[8];
#pragma unroll
        for (int c = 0; c < 8; ++c) {
            acc0[c] = make_float2(0.f, 0.f);
            acc1[c] = make_float2(0.f, 0.f);
        }
#pragma unroll
        for (int ch = 0; ch < 4; ++ch) {        // 4 chunks of 16 dims
            float2 xa[8], xb[8];
            *(float4*)(&xa[0]) = *(const float4*)(x0 + ch * 16);
            *(float4*)(&xa[2]) = *(const float4*)(x0 + ch * 16 + 4);
            *(float4*)(&xa[4]) = *(const float4*)(x0 + ch * 16 + 8);
            *(float4*)(&xa[6]) = *(const float4*)(x0 + ch * 16 + 12);
            *(float4*)(&xb[0]) = *(const float4*)(x1 + ch * 16);
            *(float4*)(&xb[2]) = *(const float4*)(x1 + ch * 16 + 4);
            *(float4*)(&xb[4]) = *(const float4*)(x1 + ch * 16 + 8);
            *(float4*)(&xb[6]) = *(const float4*)(x1 + ch * 16 + 12);
#pragma unroll
            for (int c = 0; c < 8; ++c) {
                // 64B run of e -> s_load_dwordx16; feeds 16 pk (2 rows)
                const float2* ep = (const float2*)(emb + (k0 + kg + c) * DIM + ch * 16);
                float2 ev[8];
#pragma unroll
                for (int j = 0; j < 8; ++j) ev[j] = ep[j];
#pragma unroll
                for (int j = 0; j < 8; ++j) {
                    asm("v_pk_fma_f32 %0, %1, %2, %0"
                        : "+v"(acc0[c]) : "s"(ev[j]), "v"(xa[j]));
                    asm("v_pk_fma_f32 %0, %1, %2, %0"
                        : "+v"(acc1[c]) : "s"(ev[j]), "v"(xb[j]));
                }
            }
        }
#pragma unroll
        for (int c = 0; c < 8; ++c) {
            const int k = k0 + kg + c;
            const float e2v = e2[k];
            const float d0 = fmaf(-2.f, acc0[c].x + acc0[c].y, e2v);
            const float d1 = fmaf(-2.f, acc1[c].x + acc1[c].y, e2v);
            if (d0 < best0) { best0 = d0; bk0 = k; }   // strict < : first occurrence
            if (d1 < best1) { best1 = d1; bk1 = k; }
        }
    }

    bwd[w][l]      = best0;  bwk[w][l]      = (unsigned short)bk0;
    bwd[w][l + 64] = best1;  bwk[w][l + 64] = (unsigned short)bk1;
    __syncthreads();

    // ---- lex-merge across the 8 waves (k-ranges ascending); write partial ----
    if (t < RPB) {
        float bb = bwd[0][t]; int bk = bwk[0][t];
#pragma unroll
        for (int s = 1; s < 8; ++s) {
            const float d = bwd[s][t]; const int k = bwk[s][t];
            if (d < bb || (d == bb && k < bk)) { bb = d; bk = k; }
        }
        const int row = row0 + t;
        ws[WS_PD + kh * N_ROWS + row] = bb;
        reinterpret_cast<int*>(ws)[WS_PK + kh * N_ROWS + row] = bk;
    }
}

// ---- merge 2 partials, gather, STE write, loss, counts (r6-proven shape) ----
__global__ __launch_bounds__(256, 4) void vq_epilogue(
    const float* __restrict__ in, const float* __restrict__ emb,
    float* __restrict__ out, float* __restrict__ ws)
{
    const int tid = threadIdx.x;
    const int row = blockIdx.x * 64 + (tid & 63);
    const int cg  = tid >> 6;          // 0..3 -> channels [16*cg, 16*cg+16)
    const int b   = row >> 10;
    const int hw  = row & 1023;

    const int* pk = reinterpret_cast<const int*>(ws) + WS_PK;
    float best  = ws[WS_PD + row];
    int   bestk = pk[row];
    {   // second half: k-range strictly higher -> tie keeps first (lower k)
        const float d = ws[WS_PD + N_ROWS + row];
        const int   k = pk[N_ROWS + row];
        if (d < best) { best = d; bestk = k; }
    }

    if (cg == 0)
        atomicAdd(reinterpret_cast<unsigned int*>(ws) + WS_CNT + bestk, 1u);

    const float*  xin  = in  + b * (DIM * HW) + hw;
    float*        outp = out + b * (DIM * HW) + hw;
    const float4* eq   = reinterpret_cast<const float4*>(emb + bestk * DIM + 16 * cg);

    float lsum = 0.f;
#pragma unroll
    for (int i = 0; i < 4; ++i) {
        const float4 q = eq[i];
        const int c0 = 16 * cg + 4 * i;
        const float x0 = xin[(c0 + 0) * HW];
        const float x1 = xin[(c0 + 1) * HW];
        const float x2 = xin[(c0 + 2) * HW];
        const float x3 = xin[(c0 + 3) * HW];
        const float d0 = q.x - x0, d1 = q.y - x1, d2 = q.z - x2, d3 = q.w - x3;
        lsum += d0 * d0 + d1 * d1 + d2 * d2 + d3 * d3;
        outp[(c0 + 0) * HW] = x0 + d0;   // STE: x + (q - x)
        outp[(c0 + 1) * HW] = x1 + d1;
        outp[(c0 + 2) * HW] = x2 + d2;
        outp[(c0 + 3) * HW] = x3 + d3;
    }

#pragma unroll
    for (int off = 32; off; off >>= 1) lsum += __shfl_down(lsum, off, 64);
    __shared__ float lred[4];
    if ((tid & 63) == 0) lred[tid >> 6] = lsum;
    __syncthreads();
    if (tid == 0)
        atomicAdd(ws + WS_LOSS, (lred[0] + lred[1]) + (lred[2] + lred[3]));
}

// ---- fallback if ws too small: r14 fused main (bench-proven 115us) ----
__global__ __launch_bounds__(512, 2) void vq_fused(
    const float* __restrict__ in, const float* __restrict__ emb,
    float* __restrict__ out, float* __restrict__ ws)
{
    __shared__ __align__(16) float xs[RPB * 68];
    __shared__ float bwd[8][RPB];
    __shared__ int   bwk[8][RPB];
    __shared__ int   fk[RPB];
    __shared__ float lred[8];

    const int t = threadIdx.x;
    const int w = t >> 6;
    const int l = t & 63;
    const int w_u = __builtin_amdgcn_readfirstlane(w);

    const int row0 = blockIdx.x * RPB;
    const int b = row0 >> 10, hw0 = row0 & 1023;
    const float* xin = in + b * (DIM * HW) + hw0;

#pragma unroll
    for (int rr = 0; rr < 2; ++rr) {
        const int r = rr * 64 + l;
#pragma unroll
        for (int cc = 0; cc < 8; ++cc) {
            const int c = w * 8 + cc;
            xs[r * 68 + c] = xin[c * HW + r];
        }
    }
    __syncthreads();

    const float* e2 = ws + WS_E2;
    const float* x0 = xs + l * 68;
    const float* x1 = xs + (l + 64) * 68;
    float best0 = 3.4e38f, best1 = 3.4e38f;
    int   bk0 = 0, bk1 = 0;
    const int k0 = w_u * 128;

    for (int kg = 0; kg < 128; kg += 8) {
        float2 acc0[8], acc1[8];
#pragma unroll
        for (int c = 0; c < 8; ++c) {
            acc0[c] = make_float2(0.f, 0.f);
            acc1[c] = make_float2(0.f, 0.f);
        }
#pragma unroll
        for (int ch = 0; ch < 4; ++ch) {
            float2 xa[8], xb[8];
            *(float4*)(&xa[0]) = *(const float4*)(x0 + ch * 16);
            *(float4*)(&xa[2]) = *(const float4*)(x0 + ch * 16 + 4);
            *(float4*)(&xa[4]) = *(const float4*)(x0 + ch * 16 + 8);
            *(float4*)(&xa[6]) = *(const float4*)(x0 + ch * 16 + 12);
            *(float4*)(&xb[0]) = *(const float4*)(x1 + ch * 16);
            *(float4*)(&xb[2]) = *(const float4*)(x1 + ch * 16 + 4);
            *(float4*)(&xb[4]) = *(const float4*)(x1 + ch * 16 + 8);
            *(float4*)(&xb[6]) = *(const float4*)(x1 + ch * 16 + 12);
#pragma unroll
            for (int c = 0; c < 8; ++c) {
                const float2* ep = (const float2*)(emb + (k0 + kg + c) * DIM + ch * 16);
                float2 ev[8];
#pragma unroll
                for (int j = 0; j < 8; ++j) ev[j] = ep[j];
#pragma unroll
                for (int j = 0; j < 8; ++j) {
                    asm("v_pk_fma_f32 %0, %1, %2, %0"
                        : "+v"(acc0[c]) : "s"(ev[j]), "v"(xa[j]));
                    asm("v_pk_fma_f32 %0, %1, %2, %0"
                        : "+v"(acc1[c]) : "s"(ev[j]), "v"(xb[j]));
                }
            }
        }
#pragma unroll
        for (int c = 0; c < 8; ++c) {
            const int k = k0 + kg + c;
            const float e2v = e2[k];
            const float d0 = fmaf(-2.f, acc0[c].x + acc0[c].y, e2v);
            const float d1 = fmaf(-2.f, acc1[c].x + acc1[c].y, e2v);
            if (d0 < best0) { best0 = d0; bk0 = k; }
            if (d1 < best1) { best1 = d1; bk1 = k; }
        }
    }

    bwd[w][l]      = best0;  bwk[w][l]      = bk0;
    bwd[w][l + 64] = best1;  bwk[w][l + 64] = bk1;
    __syncthreads();

    if (t < RPB) {
        float bb = bwd[0][t]; int bk = bwk[0][t];
#pragma unroll
        for (int s = 1; s < 8; ++s) {
            const float d = bwd[s][t]; const int k = bwk[s][t];
            if (d < bb || (d == bb && k < bk)) { bb = d; bk = k; }
        }
        fk[t] = bk;
        atomicAdd(reinterpret_cast<unsigned int*>(ws) + WS_CNT + bk, 1u);
    }
    __syncthreads();

    float* outp = out + b * (DIM * HW) + hw0;
    float lsum = 0.f;
#pragma unroll
    for (int rr = 0; rr < 2; ++rr) {
        const int r = rr * 64 + l;
        const int bk = fk[r];
        const float4* eq = reinterpret_cast<const float4*>(emb + bk * DIM + w * 8);
        const float* xrow = xs + r * 68;
#pragma unroll
        for (int i = 0; i < 2; ++i) {
            const float4 q = eq[i];
            const int c0 = w * 8 + 4 * i;
            const float4 xq = *(const float4*)(xrow + c0);
            const float d0 = q.x - xq.x, d1 = q.y - xq.y;
            const float d2 = q.z - xq.z, d3 = q.w - xq.w;
            lsum += d0 * d0 + d1 * d1 + d2 * d2 + d3 * d3;
            outp[(c0 + 0) * HW + r] = xq.x + d0;
            outp[(c0 + 1) * HW + r] = xq.y + d1;
            outp[(c0 + 2) * HW + r] = xq.z + d2;
            outp[(c0 + 3) * HW + r] = xq.w + d3;
        }
    }

#pragma unroll
    for (int off = 32; off; off >>= 1) lsum += __shfl_down(lsum, off, 64);
    if (l == 0) lred[w] = lsum;
    __syncthreads();
    if (t == 0) {
        float s = 0.f;
#pragma unroll
        for (int i = 0; i < 8; ++i) s += lred[i];
        atomicAdd(ws + WS_LOSS, s);
    }
}

__global__ void vq_final(float* __restrict__ out, const float* __restrict__ ws) {
    __shared__ float red[16];
    const int t = threadIdx.x;  // 1024 threads
    const unsigned int* counts = reinterpret_cast<const unsigned int*>(ws) + WS_CNT;
    float p = (float)counts[t] * (1.0f / 65536.f);
    float v = p * logf(p + 1e-10f);
#pragma unroll
    for (int off = 32; off; off >>= 1) v += __shfl_down(v, off, 64);
    if ((t & 63) == 0) red[t >> 6] = v;
    __syncthreads();
    if (t == 0) {
        float s = 0.f;
#pragma unroll
        for (int i = 0; i < 16; ++i) s += red[i];
        out[OUT_ELEMS]     = 0.25f * (1.0f / (float)OUT_ELEMS) * ws[WS_LOSS];
        out[OUT_ELEMS + 1] = expf(-s);
    }
}

extern "C" void kernel_launch(void* const* d_in, const int* in_sizes, int n_in,
                              void* d_out, int out_size, void* d_ws, size_t ws_size,
                              hipStream_t stream) {
    const float* in  = (const float*)d_in[0];
    const float* emb = (const float*)d_in[1];
    float* out = (float*)d_out;
    float* ws  = (float*)d_ws;

    vq_init<<<4, 256, 0, stream>>>(emb, ws);
    if (ws_size >= WS_NEED_BYTES) {
        vq_argmin<<<(N_ROWS / RPB) * 2, 512, 0, stream>>>(in, emb, ws);
        vq_epilogue<<<N_ROWS / 64, 256, 0, stream>>>(in, emb, out, ws);
    } else {
        vq_fused<<<N_ROWS / RPB, 512, 0, stream>>>(in, emb, out, ws);
    }
    vq_final<<<1, 1024, 0, stream>>>(out, ws);
}

// Round 18
// 121.752 us; speedup vs baseline: 1.8184x; 1.8184x over previous
//
#include <hip/hip_runtime.h>
#include <stdint.h>

// VectorQuantizer (eval fwd): inputs [64,64,32,32] f32 NCHW, embedding [1024,64] f32.
// Outputs concatenated: quantized [64,64,32,32] f32, loss scalar, perplexity scalar.
//
// Round-18 = round-14 (bench-best 115us) + INTERLEAVED wave k-ranges.
//  r13/r14/r17 invariant: VALU busy-time ~71us, utilization capped ~58% with
//  ALL waves stalling together. Hypothesis: scalar-cache thrash -- 8 waves
//  each streaming a DIFFERENT 32KB k-range cycles the 256KB codebook through
//  the ~16KB sK$ -> every s_load_dwordx16 misses to L2 (~200cyc), correlated.
//  Fix: wave w scans codes {k = w mod 8}, ascending (k = w + 64*kg + 8*c).
//  At any instant the 8 waves read 8 CONSECUTIVE codes (2KB shared window)
//  -> sK$ hits for ~7/8 of scalar fetches.
//  Correctness: within-wave ascending k + strict < ; cross-wave merge is
//  lexicographic (dist, k) -> global first-occurrence argmin unchanged.
//  Everything else identical to r14: 512-thread blocks, 8 waves, 128 rows
//  (2 rows/thread), grid 512, __launch_bounds__(512,2) (VGPR budget 128,
//  measured law: budget = 2048/(8*arg2)); e via readfirstlane-uniform
//  s_load_dwordx16 runs; x from LDS tile.
// dist = ||e||^2 - 2 x.e; 2-chain pk summation (r13/r14-proven, absmax 0.0).

#define K_CODES 1024
#define DIM 64
#define HW 1024          // 32*32
#define N_ROWS 65536
#define OUT_ELEMS 4194304
#define XSTR 68          // x row stride in dwords
#define RPB 128          // rows per block

// ws layout (float indices)
#define WS_E2   0        // 1024 f32: ||e_k||^2
#define WS_CNT  1024     // 1024 u32: counts
#define WS_LOSS 2048     // 1 f32

__global__ void vq_init(const float* __restrict__ emb, float* __restrict__ ws) {
    const int k = blockIdx.x * blockDim.x + threadIdx.x;  // 1024 threads total
    if (k < K_CODES) {
        const float4* e4 = reinterpret_cast<const float4*>(emb + k * DIM);
        float s = 0.f;
#pragma unroll
        for (int i = 0; i < DIM / 4; ++i) {
            float4 v = e4[i];
            s += v.x * v.x + v.y * v.y + v.z * v.z + v.w * v.w;
        }
        ws[WS_E2 + k] = s;
        reinterpret_cast<unsigned int*>(ws)[WS_CNT + k] = 0u;
    }
    if (blockIdx.x == 0 && threadIdx.x == 0) ws[WS_LOSS] = 0.f;
}

__global__ __launch_bounds__(512, 2) void vq_main(
    const float* __restrict__ in, const float* __restrict__ emb,
    float* __restrict__ out, float* __restrict__ ws)
{
    __shared__ __align__(16) float xs[RPB * XSTR];   // 34816 B
    __shared__ float bwd[8][RPB];
    __shared__ int   bwk[8][RPB];
    __shared__ int   fk[RPB];
    __shared__ float lred[8];

    const int t = threadIdx.x;
    const int w = t >> 6;        // wave id 0..7
    const int l = t & 63;
    const int w_u = __builtin_amdgcn_readfirstlane(w);   // SGPR wave id

    const int row0 = blockIdx.x * RPB;
    const int b = row0 >> 10, hw0 = row0 & 1023;   // 128 | 1024 -> rows stay in one b
    const float* xin = in + b * (DIM * HW) + hw0;

    // ---- stage x tile: thread (w,l): rows l and l+64, channels [8w, 8w+8) ----
#pragma unroll
    for (int rr = 0; rr < 2; ++rr) {
        const int r = rr * 64 + l;
#pragma unroll
        for (int cc = 0; cc < 8; ++cc) {
            const int c = w * 8 + cc;
            xs[r * XSTR + c] = xin[c * HW + r];   // lanes l consecutive -> coalesced
        }
    }
    __syncthreads();

    // ---- argmin: wave w scans codes k = w (mod 8), ascending ----
    const float* e2 = ws + WS_E2;
    const float* x0 = xs + l * XSTR;
    const float* x1 = xs + (l + 64) * XSTR;
    float best0 = 3.4e38f, best1 = 3.4e38f;
    int   bk0 = 0, bk1 = 0;

    for (int kg = 0; kg < 16; ++kg) {
        const int kbase = w_u + 64 * kg;        // codes kbase + 8*c, c=0..7
        float2 acc0[8], acc1[8];
#pragma unroll
        for (int c = 0; c < 8; ++c) {
            acc0[c] = make_float2(0.f, 0.f);
            acc1[c] = make_float2(0.f, 0.f);
        }
#pragma unroll
        for (int ch = 0; ch < 4; ++ch) {        // 4 chunks of 16 dims
            float2 xa[8], xb[8];
            *(float4*)(&xa[0]) = *(const float4*)(x0 + ch * 16);
            *(float4*)(&xa[2]) = *(const float4*)(x0 + ch * 16 + 4);
            *(float4*)(&xa[4]) = *(const float4*)(x0 + ch * 16 + 8);
            *(float4*)(&xa[6]) = *(const float4*)(x0 + ch * 16 + 12);
            *(float4*)(&xb[0]) = *(const float4*)(x1 + ch * 16);
            *(float4*)(&xb[2]) = *(const float4*)(x1 + ch * 16 + 4);
            *(float4*)(&xb[4]) = *(const float4*)(x1 + ch * 16 + 8);
            *(float4*)(&xb[6]) = *(const float4*)(x1 + ch * 16 + 12);
#pragma unroll
            for (int c = 0; c < 8; ++c) {
                // 64B run of e -> s_load_dwordx16; 8 waves read 8 consecutive
                // codes at any instant -> shared 2KB sK$ window
                const float2* ep = (const float2*)(emb + (kbase + 8 * c) * DIM + ch * 16);
                float2 ev[8];
#pragma unroll
                for (int j = 0; j < 8; ++j) ev[j] = ep[j];
#pragma unroll
                for (int j = 0; j < 8; ++j) {
                    asm("v_pk_fma_f32 %0, %1, %2, %0"
                        : "+v"(acc0[c]) : "s"(ev[j]), "v"(xa[j]));
                    asm("v_pk_fma_f32 %0, %1, %2, %0"
                        : "+v"(acc1[c]) : "s"(ev[j]), "v"(xb[j]));
                }
            }
        }
#pragma unroll
        for (int c = 0; c < 8; ++c) {
            const int k = kbase + 8 * c;        // ascending within wave
            const float e2v = e2[k];
            const float d0 = fmaf(-2.f, acc0[c].x + acc0[c].y, e2v);
            const float d1 = fmaf(-2.f, acc1[c].x + acc1[c].y, e2v);
            if (d0 < best0) { best0 = d0; bk0 = k; }   // strict < : first occurrence
            if (d1 < best1) { best1 = d1; bk1 = k; }
        }
    }

    bwd[w][l]      = best0;  bwk[w][l]      = bk0;
    bwd[w][l + 64] = best1;  bwk[w][l + 64] = bk1;
    __syncthreads();

    // ---- lex-merge across the 8 waves: (dist, k) min == first occurrence ----
    if (t < RPB) {
        float bb = bwd[0][t]; int bk = bwk[0][t];
#pragma unroll
        for (int s = 1; s < 8; ++s) {
            const float d = bwd[s][t]; const int k = bwk[s][t];
            if (d < bb || (d == bb && k < bk)) { bb = d; bk = k; }
        }
        fk[t] = bk;
        atomicAdd(reinterpret_cast<unsigned int*>(ws) + WS_CNT + bk, 1u);
    }
    __syncthreads();

    // ---- fused epilogue: thread (w,l): rows l, l+64, channels [8w, 8w+8) ----
    float* outp = out + b * (DIM * HW) + hw0;
    float lsum = 0.f;
#pragma unroll
    for (int rr = 0; rr < 2; ++rr) {
        const int r = rr * 64 + l;
        const int bk = fk[r];
        const float4* eq = reinterpret_cast<const float4*>(emb + bk * DIM + w * 8);
        const float* xrow = xs + r * XSTR;
#pragma unroll
        for (int i = 0; i < 2; ++i) {
            const float4 q = eq[i];
            const int c0 = w * 8 + 4 * i;
            const float4 xq = *(const float4*)(xrow + c0);  // aligned
            const float d0 = q.x - xq.x, d1 = q.y - xq.y;
            const float d2 = q.z - xq.z, d3 = q.w - xq.w;
            lsum += d0 * d0 + d1 * d1 + d2 * d2 + d3 * d3;
            outp[(c0 + 0) * HW + r] = xq.x + d0;   // STE: x + (q - x)
            outp[(c0 + 1) * HW + r] = xq.y + d1;
            outp[(c0 + 2) * HW + r] = xq.z + d2;
            outp[(c0 + 3) * HW + r] = xq.w + d3;
        }
    }

#pragma unroll
    for (int off = 32; off; off >>= 1) lsum += __shfl_down(lsum, off, 64);
    if (l == 0) lred[w] = lsum;
    __syncthreads();
    if (t == 0) {
        float s = 0.f;
#pragma unroll
        for (int i = 0; i < 8; ++i) s += lred[i];
        atomicAdd(ws + WS_LOSS, s);
    }
}

__global__ void vq_final(float* __restrict__ out, const float* __restrict__ ws) {
    __shared__ float red[16];
    const int t = threadIdx.x;  // 1024 threads
    const unsigned int* counts = reinterpret_cast<const unsigned int*>(ws) + WS_CNT;
    float p = (float)counts[t] * (1.0f / 65536.f);
    float v = p * logf(p + 1e-10f);
#pragma unroll
    for (int off = 32; off; off >>= 1) v += __shfl_down(v, off, 64);
    if ((t & 63) == 0) red[t >> 6] = v;
    __syncthreads();
    if (t == 0) {
        float s = 0.f;
#pragma unroll
        for (int i = 0; i < 16; ++i) s += red[i];
        out[OUT_ELEMS]     = 0.25f * (1.0f / (float)OUT_ELEMS) * ws[WS_LOSS];
        out[OUT_ELEMS + 1] = expf(-s);
    }
}

extern "C" void kernel_launch(void* const* d_in, const int* in_sizes, int n_in,
                              void* d_out, int out_size, void* d_ws, size_t ws_size,
                              hipStream_t stream) {
    const float* in  = (const float*)d_in[0];
    const float* emb = (const float*)d_in[1];
    float* out = (float*)d_out;
    float* ws  = (float*)d_ws;

    vq_init<<<4, 256, 0, stream>>>(emb, ws);
    vq_main<<<N_ROWS / RPB, 512, 0, stream>>>(in, emb, out, ws);
    vq_final<<<1, 1024, 0, stream>>>(out, ws);
}

// Round 19
// 115.214 us; speedup vs baseline: 1.9216x; 1.0567x over previous
//
#include <hip/hip_runtime.h>
#include <stdint.h>

// VectorQuantizer (eval fwd): inputs [64,64,32,32] f32 NCHW, embedding [1024,64] f32.
// Outputs concatenated: quantized [64,64,32,32] f32, loss scalar, perplexity scalar.
//
// Round-19: exact revert to round 14 -- the bench-best configuration (115.2us).
//  Evidence r13-r18 (six schedules): VALU busy-time invariant ~71-74us
//  (= 54.6us pk-FMA floor + ~16us argmin bookkeeping; v_pk_fma_f32 issues at
//  4cyc/wave so 157.3TF is the packed fp32 rate -- no fp32 MFMA on CDNA4).
//  Best utilization 58% (this config); TLP (r17), sK$ locality (r18), deeper
//  reuse at 2 waves/SIMD (r16) all failed to beat it -- residual stall is the
//  shared-lgkmcnt serialization between ds_read(x) and s_load(e).
//  Structure: 512-thread blocks, 8 waves x 128-code ranges, 128 rows/block
//  (2 rows/thread), grid 512; __launch_bounds__(512,2) -> VGPR budget 128
//  (measured law: budget = 2048/(8*arg2)); e via readfirstlane-uniform
//  s_load_dwordx16 64B runs; x from LDS tile; fused merge+epilogue.
// dist = ||e||^2 - 2 x.e; absmax 0.0 across rounds 2-18.

#define K_CODES 1024
#define DIM 64
#define HW 1024          // 32*32
#define N_ROWS 65536
#define OUT_ELEMS 4194304
#define XSTR 68          // x row stride in dwords
#define RPB 128          // rows per block

// ws layout (float indices)
#define WS_E2   0        // 1024 f32: ||e_k||^2
#define WS_CNT  1024     // 1024 u32: counts
#define WS_LOSS 2048     // 1 f32

__global__ void vq_init(const float* __restrict__ emb, float* __restrict__ ws) {
    const int k = blockIdx.x * blockDim.x + threadIdx.x;  // 1024 threads total
    if (k < K_CODES) {
        const float4* e4 = reinterpret_cast<const float4*>(emb + k * DIM);
        float s = 0.f;
#pragma unroll
        for (int i = 0; i < DIM / 4; ++i) {
            float4 v = e4[i];
            s += v.x * v.x + v.y * v.y + v.z * v.z + v.w * v.w;
        }
        ws[WS_E2 + k] = s;
        reinterpret_cast<unsigned int*>(ws)[WS_CNT + k] = 0u;
    }
    if (blockIdx.x == 0 && threadIdx.x == 0) ws[WS_LOSS] = 0.f;
}

__global__ __launch_bounds__(512, 2) void vq_main(
    const float* __restrict__ in, const float* __restrict__ emb,
    float* __restrict__ out, float* __restrict__ ws)
{
    __shared__ __align__(16) float xs[RPB * XSTR];   // 34816 B
    __shared__ float bwd[8][RPB];
    __shared__ int   bwk[8][RPB];
    __shared__ int   fk[RPB];
    __shared__ float lred[8];

    const int t = threadIdx.x;
    const int w = t >> 6;        // wave id 0..7
    const int l = t & 63;
    const int w_u = __builtin_amdgcn_readfirstlane(w);   // SGPR wave id

    const int row0 = blockIdx.x * RPB;
    const int b = row0 >> 10, hw0 = row0 & 1023;   // 128 | 1024 -> rows stay in one b
    const float* xin = in + b * (DIM * HW) + hw0;

    // ---- stage x tile: thread (w,l): rows l and l+64, channels [8w, 8w+8) ----
#pragma unroll
    for (int rr = 0; rr < 2; ++rr) {
        const int r = rr * 64 + l;
#pragma unroll
        for (int cc = 0; cc < 8; ++cc) {
            const int c = w * 8 + cc;
            xs[r * XSTR + c] = xin[c * HW + r];   // lanes l consecutive -> coalesced
        }
    }
    __syncthreads();

    // ---- argmin over this wave's 128 codes for BOTH rows (k0 wave-uniform) ----
    const float* e2 = ws + WS_E2;
    const float* x0 = xs + l * XSTR;
    const float* x1 = xs + (l + 64) * XSTR;
    float best0 = 3.4e38f, best1 = 3.4e38f;
    int   bk0 = 0, bk1 = 0;
    const int k0 = w_u * 128;

    for (int kg = 0; kg < 128; kg += 8) {
        float2 acc0[8], acc1[8];
#pragma unroll
        for (int c = 0; c < 8; ++c) {
            acc0[c] = make_float2(0.f, 0.f);
            acc1[c] = make_float2(0.f, 0.f);
        }
#pragma unroll
        for (int ch = 0; ch < 4; ++ch) {        // 4 chunks of 16 dims
            float2 xa[8], xb[8];
            *(float4*)(&xa[0]) = *(const float4*)(x0 + ch * 16);
            *(float4*)(&xa[2]) = *(const float4*)(x0 + ch * 16 + 4);
            *(float4*)(&xa[4]) = *(const float4*)(x0 + ch * 16 + 8);
            *(float4*)(&xa[6]) = *(const float4*)(x0 + ch * 16 + 12);
            *(float4*)(&xb[0]) = *(const float4*)(x1 + ch * 16);
            *(float4*)(&xb[2]) = *(const float4*)(x1 + ch * 16 + 4);
            *(float4*)(&xb[4]) = *(const float4*)(x1 + ch * 16 + 8);
            *(float4*)(&xb[6]) = *(const float4*)(x1 + ch * 16 + 12);
#pragma unroll
            for (int c = 0; c < 8; ++c) {
                // 64B run of e -> s_load_dwordx16; feeds 16 pk (2 rows)
                const float2* ep = (const float2*)(emb + (k0 + kg + c) * DIM + ch * 16);
                float2 ev[8];
#pragma unroll
                for (int j = 0; j < 8; ++j) ev[j] = ep[j];
#pragma unroll
                for (int j = 0; j < 8; ++j) {
                    asm("v_pk_fma_f32 %0, %1, %2, %0"
                        : "+v"(acc0[c]) : "s"(ev[j]), "v"(xa[j]));
                    asm("v_pk_fma_f32 %0, %1, %2, %0"
                        : "+v"(acc1[c]) : "s"(ev[j]), "v"(xb[j]));
                }
            }
        }
#pragma unroll
        for (int c = 0; c < 8; ++c) {
            const int k = k0 + kg + c;
            const float e2v = e2[k];
            const float d0 = fmaf(-2.f, acc0[c].x + acc0[c].y, e2v);
            const float d1 = fmaf(-2.f, acc1[c].x + acc1[c].y, e2v);
            if (d0 < best0) { best0 = d0; bk0 = k; }   // strict < : first occurrence
            if (d1 < best1) { best1 = d1; bk1 = k; }
        }
    }

    bwd[w][l]      = best0;  bwk[w][l]      = bk0;
    bwd[w][l + 64] = best1;  bwk[w][l + 64] = bk1;
    __syncthreads();

    // ---- lex-merge across the 8 waves (k-ranges ascending) ----
    if (t < RPB) {
        float bb = bwd[0][t]; int bk = bwk[0][t];
#pragma unroll
        for (int s = 1; s < 8; ++s) {
            const float d = bwd[s][t]; const int k = bwk[s][t];
            if (d < bb || (d == bb && k < bk)) { bb = d; bk = k; }
        }
        fk[t] = bk;
        atomicAdd(reinterpret_cast<unsigned int*>(ws) + WS_CNT + bk, 1u);
    }
    __syncthreads();

    // ---- fused epilogue: thread (w,l): rows l, l+64, channels [8w, 8w+8) ----
    float* outp = out + b * (DIM * HW) + hw0;
    float lsum = 0.f;
#pragma unroll
    for (int rr = 0; rr < 2; ++rr) {
        const int r = rr * 64 + l;
        const int bk = fk[r];
        const float4* eq = reinterpret_cast<const float4*>(emb + bk * DIM + w * 8);
        const float* xrow = xs + r * XSTR;
#pragma unroll
        for (int i = 0; i < 2; ++i) {
            const float4 q = eq[i];
            const int c0 = w * 8 + 4 * i;
            const float4 xq = *(const float4*)(xrow + c0);  // aligned
            const float d0 = q.x - xq.x, d1 = q.y - xq.y;
            const float d2 = q.z - xq.z, d3 = q.w - xq.w;
            lsum += d0 * d0 + d1 * d1 + d2 * d2 + d3 * d3;
            outp[(c0 + 0) * HW + r] = xq.x + d0;   // STE: x + (q - x)
            outp[(c0 + 1) * HW + r] = xq.y + d1;
            outp[(c0 + 2) * HW + r] = xq.z + d2;
            outp[(c0 + 3) * HW + r] = xq.w + d3;
        }
    }

#pragma unroll
    for (int off = 32; off; off >>= 1) lsum += __shfl_down(lsum, off, 64);
    if (l == 0) lred[w] = lsum;
    __syncthreads();
    if (t == 0) {
        float s = 0.f;
#pragma unroll
        for (int i = 0; i < 8; ++i) s += lred[i];
        atomicAdd(ws + WS_LOSS, s);
    }
}

__global__ void vq_final(float* __restrict__ out, const float* __restrict__ ws) {
    __shared__ float red[16];
    const int t = threadIdx.x;  // 1024 threads
    const unsigned int* counts = reinterpret_cast<const unsigned int*>(ws) + WS_CNT;
    float p = (float)counts[t] * (1.0f / 65536.f);
    float v = p * logf(p + 1e-10f);
#pragma unroll
    for (int off = 32; off; off >>= 1) v += __shfl_down(v, off, 64);
    if ((t & 63) == 0) red[t >> 6] = v;
    __syncthreads();
    if (t == 0) {
        float s = 0.f;
#pragma unroll
        for (int i = 0; i < 16; ++i) s += red[i];
        out[OUT_ELEMS]     = 0.25f * (1.0f / (float)OUT_ELEMS) * ws[WS_LOSS];
        out[OUT_ELEMS + 1] = expf(-s);
    }
}

extern "C" void kernel_launch(void* const* d_in, const int* in_sizes, int n_in,
                              void* d_out, int out_size, void* d_ws, size_t ws_size,
                              hipStream_t stream) {
    const float* in  = (const float*)d_in[0];
    const float* emb = (const float*)d_in[1];
    float* out = (float*)d_out;
    float* ws  = (float*)d_ws;

    vq_init<<<4, 256, 0, stream>>>(emb, ws);
    vq_main<<<N_ROWS / RPB, 512, 0, stream>>>(in, emb, out, ws);
    vq_final<<<1, 1024, 0, stream>>>(out, ws);
}